// Round 2
// baseline (3091.714 us; speedup 1.0000x reference)
//
#include <hip/hip_runtime.h>
#include <hip/hip_bf16.h>

#define B_ 2
#define L_ 1024
#define D_ 768
#define H_ 12
#define HD_ 64
#define NL_ 2
#define DFF_ 3072
#define V_ 50257
#define EOS_ 50256
#define TD_ (3 * D_)
#define BL_ (B_ * L_)

typedef __attribute__((ext_vector_type(8))) short bf16x8_t;
typedef __attribute__((ext_vector_type(4))) float f32x4_t;

__device__ __forceinline__ unsigned short f2bf(float f) {
  union { float f; unsigned int i; } c;
  c.f = f;
  unsigned int x = c.i;
  unsigned int lsb = (x >> 16) & 1u;
  x += 0x7fffu + lsb;
  return (unsigned short)(x >> 16);
}

// ---------------------------------------------------------------------------
// f32 -> bf16 bulk convert (vectorized by 4)
__global__ void cvt_kernel(const float* __restrict__ in,
                           unsigned short* __restrict__ out, int n4) {
  int i = blockIdx.x * blockDim.x + threadIdx.x;
  if (i >= n4) return;
  f32x4_t v = *(const f32x4_t*)(in + (size_t)i * 4);
  ushort4 o;
  o.x = f2bf(v[0]); o.y = f2bf(v[1]); o.z = f2bf(v[2]); o.w = f2bf(v[3]);
  *(ushort4*)(out + (size_t)i * 4) = o;
}

// ---------------------------------------------------------------------------
// rel_idx: rel[l] = l - last_eos_pos(<=l), 0 if none. Serial scan per batch row.
__global__ void prep_kernel(const int* __restrict__ ids, int* __restrict__ rel) {
  int b = threadIdx.x;
  if (b >= B_) return;
  int last = 0;
  for (int l = 0; l < L_; ++l) {
    int id = ids[b * L_ + l];
    if (id == EOS_) last = l;
    rel[b * L_ + l] = l - last;
  }
}

// ---------------------------------------------------------------------------
// x = tok_emb[ids]*sqrt(D) + pos_emb[rel]; write f32 and bf16 shadow.
__global__ void embed_kernel(const int* __restrict__ ids,
                             const float* __restrict__ tok,
                             const float* __restrict__ pos,
                             const int* __restrict__ rel,
                             float* __restrict__ x,
                             unsigned short* __restrict__ xb) {
  int i = blockIdx.x * blockDim.x + threadIdx.x;
  if (i >= BL_ * D_) return;
  int d = i % D_;
  int bl = i / D_;
  int id = ids[bl];
  int r = rel[bl];
  float val = tok[(size_t)id * D_ + d] * 27.712812921102035f +
              pos[(size_t)r * D_ + d];
  x[i] = val;
  xb[i] = f2bf(val);
}

// ---------------------------------------------------------------------------
// C[M,N] = A[M,K] @ W[N,K]^T + bias.  A bf16; W bf16 or f32 (inline cvt); C f32.
// Block: 256 thr = 4 waves; tile 64(M) x 64(N); wave w -> rows w*16..w*16+15.
// MFMA 16x16x32 bf16:  A frag: m=lane&15, k=(lane>>4)*8+j (8 contiguous)
//                      B frag: n=lane&15, k=(lane>>4)*8+j
//                      C/D:    col=lane&15, row=(lane>>4)*4+r   [m89/m91]
template <int W_IS_F32>
__global__ __launch_bounds__(256) void gemm_bt_kernel(
    const unsigned short* __restrict__ A, const void* __restrict__ W,
    const float* __restrict__ bias, float* __restrict__ C,
    int M, int N, int K) {
  int wave = threadIdx.x >> 6;
  int lane = threadIdx.x & 63;
  int lr = lane & 15;
  int kq = (lane >> 4) << 3;
  int n0 = blockIdx.x << 6;
  int m0 = blockIdx.y << 6;
  int row = m0 + wave * 16 + lr;

  const unsigned short* arow = A + (size_t)row * K + kq;
  const unsigned short* browb[4];
  const float* browf[4];
#pragma unroll
  for (int nt = 0; nt < 4; ++nt) {
    int col = n0 + nt * 16 + lr;
    if (col >= N) col = N - 1;  // clamp load; store guarded below
    if (W_IS_F32) browf[nt] = (const float*)W + (size_t)col * K + kq;
    else          browb[nt] = (const unsigned short*)W + (size_t)col * K + kq;
  }

  f32x4_t acc[4] = {{0.f, 0.f, 0.f, 0.f},
                    {0.f, 0.f, 0.f, 0.f},
                    {0.f, 0.f, 0.f, 0.f},
                    {0.f, 0.f, 0.f, 0.f}};

  for (int k0 = 0; k0 < K; k0 += 32) {
    bf16x8_t a = *(const bf16x8_t*)(arow + k0);
#pragma unroll
    for (int nt = 0; nt < 4; ++nt) {
      bf16x8_t bfr;
      if (W_IS_F32) {
        f32x4_t w0 = *(const f32x4_t*)(browf[nt] + k0);
        f32x4_t w1 = *(const f32x4_t*)(browf[nt] + k0 + 4);
#pragma unroll
        for (int j = 0; j < 4; ++j) {
          bfr[j]     = (short)f2bf(w0[j]);
          bfr[4 + j] = (short)f2bf(w1[j]);
        }
      } else {
        bfr = *(const bf16x8_t*)(browb[nt] + k0);
      }
      acc[nt] = __builtin_amdgcn_mfma_f32_16x16x32_bf16(a, bfr, acc[nt], 0, 0, 0);
    }
  }

  int crow = m0 + wave * 16 + ((lane >> 4) << 2);
#pragma unroll
  for (int nt = 0; nt < 4; ++nt) {
    int col = n0 + nt * 16 + lr;
    if (col >= N) continue;
    float bv = bias ? bias[col] : 0.0f;
#pragma unroll
    for (int r = 0; r < 4; ++r) {
      float v = acc[nt][r] + bv;
      C[(size_t)(crow + r) * N + col] = v;
    }
  }
}

// ---------------------------------------------------------------------------
// Attention: one wave per (b, h, q). Segment-causal mask == k in [q-rel, q].
// Online softmax over 64-wide k-chunks; k/v staged in LDS (pad 65 -> no conflicts).
__global__ __launch_bounds__(64) void attn_kernel(
    const float* __restrict__ qkv, const int* __restrict__ rel,
    unsigned short* __restrict__ obf) {
  __shared__ float q_s[HD_];
  __shared__ float k_s[64][65];
  __shared__ float v_s[64][65];
  __shared__ float p_s[64];

  int lane = threadIdx.x;
  int bid = blockIdx.x;
  int q = bid % L_;
  int h = (bid / L_) % H_;
  int b = bid / (L_ * H_);
  int boff = b * L_;

  const float* qrow = qkv + (size_t)(boff + q) * TD_ + h * HD_;
  q_s[lane] = qrow[lane];
  int klo = q - rel[boff + q];

  float m = -1e30f, lsum = 0.f, o = 0.f;

  for (int base = (klo >> 6) << 6; base <= q; base += 64) {
    const float* kbase = qkv + (size_t)(boff + base) * TD_ + D_ + h * HD_;
#pragma unroll 8
    for (int r = 0; r < 64; ++r) {
      k_s[r][lane] = kbase[(size_t)r * TD_ + lane];
      v_s[r][lane] = kbase[(size_t)r * TD_ + D_ + lane];
    }
    __syncthreads();

    float s = 0.f;
#pragma unroll
    for (int d = 0; d < HD_; ++d) s += q_s[d] * k_s[lane][d];
    s *= 0.125f;  // 1/sqrt(64)
    int kpos = base + lane;
    bool valid = (kpos >= klo) && (kpos <= q);
    s = valid ? s : -1e30f;

    float cmax = s;
#pragma unroll
    for (int off = 32; off; off >>= 1) cmax = fmaxf(cmax, __shfl_xor(cmax, off, 64));
    float mnew = fmaxf(m, cmax);
    float alpha = __expf(m - mnew);  // first chunk: exp(-huge) = 0
    float p = valid ? __expf(s - mnew) : 0.f;
    p_s[lane] = p;
    float ps = p;
#pragma unroll
    for (int off = 32; off; off >>= 1) ps += __shfl_xor(ps, off, 64);
    lsum = lsum * alpha + ps;
    __syncthreads();

    o = o * alpha;
#pragma unroll 8
    for (int j = 0; j < 64; ++j) o += p_s[j] * v_s[j][lane];
    m = mnew;
    __syncthreads();
  }

  o /= lsum;
  obf[(size_t)(boff + q) * D_ + h * HD_ + lane] = f2bf(o);
}

// ---------------------------------------------------------------------------
// x = LN(x + t)*w + b; write f32 and bf16 shadow. One block (256 thr) per row.
__device__ __forceinline__ float block_reduce_sum_256(float v, float* sbuf) {
#pragma unroll
  for (int off = 32; off; off >>= 1) v += __shfl_xor(v, off, 64);
  if ((threadIdx.x & 63) == 0) sbuf[threadIdx.x >> 6] = v;
  __syncthreads();
  float r = sbuf[0] + sbuf[1] + sbuf[2] + sbuf[3];
  __syncthreads();
  return r;
}

__global__ __launch_bounds__(256) void add_ln_kernel(
    const float* __restrict__ x, const float* __restrict__ t,
    const float* __restrict__ w, const float* __restrict__ b,
    float* __restrict__ xo, unsigned short* __restrict__ xbo) {
  __shared__ float sbuf[4];
  size_t base = (size_t)blockIdx.x * D_;
  float v[3];
  float s = 0.f;
#pragma unroll
  for (int i = 0; i < 3; ++i) {
    int idx = threadIdx.x + i * 256;
    v[i] = x[base + idx] + t[base + idx];
    s += v[i];
  }
  float mean = block_reduce_sum_256(s, sbuf) * (1.f / D_);
  float vs = 0.f;
#pragma unroll
  for (int i = 0; i < 3; ++i) {
    float d = v[i] - mean;
    vs += d * d;
  }
  float var = block_reduce_sum_256(vs, sbuf) * (1.f / D_);
  float rstd = rsqrtf(var + 1e-5f);
#pragma unroll
  for (int i = 0; i < 3; ++i) {
    int idx = threadIdx.x + i * 256;
    float o = (v[i] - mean) * rstd * w[idx] + b[idx];
    xo[base + idx] = o;
    xbo[base + idx] = f2bf(o);
  }
}

// ---------------------------------------------------------------------------
__global__ void gelu_kernel(const float* __restrict__ h,
                            unsigned short* __restrict__ hb, int n) {
  int i = blockIdx.x * blockDim.x + threadIdx.x;
  if (i >= n) return;
  float x = h[i];
  float g = 0.5f * x * (1.f + erff(x * 0.7071067811865476f));
  hb[i] = f2bf(g);
}

// ---------------------------------------------------------------------------
extern "C" void kernel_launch(void* const* d_in, const int* in_sizes, int n_in,
                              void* d_out, int out_size, void* d_ws, size_t ws_size,
                              hipStream_t stream) {
  const int* ids       = (const int*)d_in[0];
  const float* tok     = (const float*)d_in[1];
  const float* pos     = (const float*)d_in[2];
  const float* qkv_w   = (const float*)d_in[3];
  const float* qkv_b   = (const float*)d_in[4];
  const float* out_w   = (const float*)d_in[5];
  const float* out_b   = (const float*)d_in[6];
  const float* ln1_w   = (const float*)d_in[7];
  const float* ln1_b   = (const float*)d_in[8];
  const float* ln2_w   = (const float*)d_in[9];
  const float* ln2_b   = (const float*)d_in[10];
  const float* ff1_w   = (const float*)d_in[11];
  const float* ff2_w   = (const float*)d_in[13];
  const float* ff2_b   = (const float*)d_in[14];
  const float* ff1_b   = (const float*)d_in[12];

  char* ws = (char*)d_ws;
  size_t off = 0;
  auto alloc = [&](size_t bytes) {
    void* p = ws + off;
    off = (off + bytes + 255) & ~(size_t)255;
    return p;
  };
  int* rel            = (int*)alloc((size_t)BL_ * 4);
  float* x            = (float*)alloc((size_t)BL_ * D_ * 4);
  unsigned short* xb  = (unsigned short*)alloc((size_t)BL_ * D_ * 2);
  // qkvbuf (live qkv->attn) and hbuf (live ff1->gelu) never overlap in time
  float* big          = (float*)alloc((size_t)BL_ * DFF_ * 4);
  float* qkvbuf       = big;
  float* hbuf         = big;
  unsigned short* obf = (unsigned short*)alloc((size_t)BL_ * D_ * 2);
  float* t            = (float*)alloc((size_t)BL_ * D_ * 4);
  unsigned short* hb  = (unsigned short*)alloc((size_t)BL_ * DFF_ * 2);
  // bf16 weight copies (both layers)
  unsigned short* qkvw_b16 = (unsigned short*)alloc((size_t)NL_ * TD_ * D_ * 2);
  unsigned short* outw_b16 = (unsigned short*)alloc((size_t)NL_ * D_ * D_ * 2);
  unsigned short* ff1w_b16 = (unsigned short*)alloc((size_t)NL_ * DFF_ * D_ * 2);
  unsigned short* ff2w_b16 = (unsigned short*)alloc((size_t)NL_ * D_ * DFF_ * 2);
  size_t base_need = off;
  unsigned short* tok_b16 = (unsigned short*)alloc((size_t)V_ * D_ * 2);
  bool have_tok = (off <= ws_size);
  (void)base_need;

  auto cvt = [&](const float* in, unsigned short* out, size_t n) {
    int n4 = (int)(n / 4);
    cvt_kernel<<<(n4 + 255) / 256, 256, 0, stream>>>(in, out, n4);
  };
  cvt(qkv_w, qkvw_b16, (size_t)NL_ * TD_ * D_);
  cvt(out_w, outw_b16, (size_t)NL_ * D_ * D_);
  cvt(ff1_w, ff1w_b16, (size_t)NL_ * DFF_ * D_);
  cvt(ff2_w, ff2w_b16, (size_t)NL_ * D_ * DFF_);
  if (have_tok) cvt(tok, tok_b16, (size_t)V_ * D_);

  prep_kernel<<<1, 64, 0, stream>>>(ids, rel);
  embed_kernel<<<(BL_ * D_ + 255) / 256, 256, 0, stream>>>(ids, tok, pos, rel, x, xb);

  for (int l = 0; l < NL_; ++l) {
    // qkv = xb @ qkv_w[l].T + qkv_b[l]   [BL, 3D]
    gemm_bt_kernel<0><<<dim3(TD_ / 64, BL_ / 64), 256, 0, stream>>>(
        xb, qkvw_b16 + (size_t)l * TD_ * D_, qkv_b + (size_t)l * TD_, qkvbuf,
        BL_, TD_, D_);
    // attention -> obf (bf16)
    attn_kernel<<<B_ * H_ * L_, 64, 0, stream>>>(qkvbuf, rel, obf);
    // t = obf @ out_w[l].T + out_b[l]
    gemm_bt_kernel<0><<<dim3(D_ / 64, BL_ / 64), 256, 0, stream>>>(
        obf, outw_b16 + (size_t)l * D_ * D_, out_b + (size_t)l * D_, t,
        BL_, D_, D_);
    // x = LN(x + t)
    add_ln_kernel<<<BL_, 256, 0, stream>>>(x, t, ln1_w + l * D_, ln1_b + l * D_, x, xb);
    // h = xb @ ff1_w[l].T + ff1_b[l]     [BL, DFF]
    gemm_bt_kernel<0><<<dim3(DFF_ / 64, BL_ / 64), 256, 0, stream>>>(
        xb, ff1w_b16 + (size_t)l * DFF_ * D_, ff1_b + (size_t)l * DFF_, hbuf,
        BL_, DFF_, D_);
    gelu_kernel<<<(BL_ * DFF_ + 255) / 256, 256, 0, stream>>>(hbuf, hb, BL_ * DFF_);
    // t = hb @ ff2_w[l].T + ff2_b[l]
    gemm_bt_kernel<0><<<dim3(D_ / 64, BL_ / 64), 256, 0, stream>>>(
        hb, ff2w_b16 + (size_t)l * D_ * DFF_, ff2_b + (size_t)l * D_, t,
        BL_, D_, DFF_);
    // x = LN(x + h)
    add_ln_kernel<<<BL_, 256, 0, stream>>>(x, t, ln2_w + l * D_, ln2_b + l * D_, x, xb);
  }

  // logits = xb @ tok_emb.T  -> f32 straight to d_out  [BL, V]
  if (have_tok) {
    gemm_bt_kernel<0><<<dim3((V_ + 63) / 64, BL_ / 64), 256, 0, stream>>>(
        xb, tok_b16, nullptr, (float*)d_out, BL_, V_, D_);
  } else {
    gemm_bt_kernel<1><<<dim3((V_ + 63) / 64, BL_ / 64), 256, 0, stream>>>(
        xb, tok, nullptr, (float*)d_out, BL_, V_, D_);
  }
}